// Round 9
// baseline (693.060 us; speedup 1.0000x reference)
//
#include <hip/hip_runtime.h>

// x:   (2,4,8,8,8,96,96) fp32   strides: b 18874368, ci 4718592, cd 589824, t 73728, d 9216, h 96, w 1
// W:   (9,4,4,3,3,3)     fp32   strides: ij 432, o 108, ci 27, kd 9, kh 3, kw 1
// b:   (9,4)             fp32
// out: (2,4,6,6,8,96,96) fp32   strides: b 10616832, o 2654208, c 442368, t 73728, d 9216, h 96, w 1
//
// Round-9: MFMA rewrite (split-bf16). Evidence: r3/r6/r8 proved every
// overhead trim neutral; scalar path pinned ~2.1x above its 262us FMA-issue
// floor with MfmaUtil=0.0 all session. Formulation per (ci, i, j):
//   D[m][n] += A[m][k] * B[k][n],  m = 16 w-positions, n = s*4+o (4 d x 4 o),
//   k = dd*9 + kh*3 + kw (6 staged d-planes x 3 x 3 = 54, padded to 64).
// d-masking is folded into B: B[k][(o,s)] = W[o][ci][p-s][kh][kw] if
// 0<=p-s<=2 else 0 (p = k/9). Precision: W,x each split hi+lo bf16; keep
// Whi*xhi + Whi*xlo + Wlo*xhi (dropped Wlo*xlo ~2^-16 rel; est err ~1e-4).
// 6 MFMAs per tile per (ci,ij): (Ahi0,Bh0)(Alo0,Bh0)(Ahi0,Bl0) + f=1 set.
// x staged in LDS pre-split as u32 (hi16<<16 | lo16); A-frags = 8 b32 reads
// + 8 pack ops per frag-pair. B-frags built per (ci,ij) into LDS by all 256
// threads (one uint4 each), loaded once per wave per (ci,ij).
// Fragment layouts (assumed AMD convention; C/D verified in docs):
//   A: lane l -> A[i=l&15][k=(l>>4)*8+e]; B: lane l -> B[k=(l>>4)*8+e][j=l&15]
//   D: lane l, reg r -> D[i=(l>>4)*4+r][j=l&15]
// Block: (b,c,t,dq,h4): 2*36*2*24 = 3456 blocks; wave wv handles h-row
// h0+wv x 6 w-tiles; acc = 6 x f32x4.

#define BLOCK 256

typedef short bf16x8 __attribute__((ext_vector_type(8)));
typedef float f32x4  __attribute__((ext_vector_type(4)));

union FA { uint32_t u[4]; bf16x8 v; };

__device__ __forceinline__ uint32_t packsplit(float x) {
    uint32_t bx = __float_as_uint(x);
    uint32_t hi = bx & 0xFFFF0000u;
    float lo = x - __uint_as_float(hi);
    return hi | (__float_as_uint(lo) >> 16);
}

__global__ __launch_bounds__(256, 4) void conv5d_mfma(
    const float* __restrict__ xg,
    const float* __restrict__ Wg,
    const float* __restrict__ bg,
    float* __restrict__ outg)
{
    __shared__ uint32_t xs[36 * 104];   // packed split x: [p(6)][hq(6)][wcol(104)]
    __shared__ uint4    Bb[256];        // B-frags: [part(2)][f(2)][lane(64)]

    // zero once: halo cols, invalid planes/rows never re-staged
    for (int k = threadIdx.x; k < 36*104; k += BLOCK) xs[k] = 0u;

    // XCD-aware decode: 3456 = 72 (b,c,t) slabs x 2 dq x 24 h4
    int bi  = blockIdx.x;
    int xcd = bi & 7;
    int g   = bi >> 3;
    int slab = xcd*9 + g/48;
    int rr  = g % 48;
    int dq  = rr / 24;               // d-quad: outputs d = dq*4 + s
    int h4  = rr % 24;
    int b   = slab / 36;
    int ct  = slab % 36;
    int c   = ct / 6;
    int t   = ct % 6;
    int h0  = h4 * 4;

    int tid  = threadIdx.x;
    int lane = tid & 63;
    int wv   = tid >> 6;             // wave -> h-row h0+wv
    int am   = lane & 15;            // A's m (w-position)
    int kg   = lane >> 4;            // k-group

    // ---- A-read offsets (loop-invariant): k = f*32 + kg*8 + e ----
    int offs[2][8];
    #pragma unroll
    for (int f = 0; f < 2; ++f) {
        #pragma unroll
        for (int e = 0; e < 8; ++e) {
            int k = f*32 + kg*8 + e;
            if (k < 54) {
                int p  = k / 9, r9 = k % 9;
                int kh = r9 / 3, kw = r9 % 3;
                // x row = staged plane p, h-row (wv+kh); w idx = x_w + 2
                offs[f][e] = (p*6 + wv + kh)*104 + am + kw + 1;
            } else {
                offs[f][e] = 0;      // pad: B is 0 there, any finite value ok
            }
        }
    }

    // ---- staging descriptors: 36 rows x 24 float4 = 864, 4 passes ----
    int goff[4], lwr[4];
    #pragma unroll
    for (int p4 = 0; p4 < 4; ++p4) {
        int u   = tid + p4*BLOCK;
        int row = u / 24, q = u % 24;
        int pp  = row / 6, hq = row % 6;
        int dd  = dq*4 - 1 + pp;     // absolute input d-plane
        int hh  = h0 - 1 + hq;
        bool ok = (u < 864) && ((unsigned)dd < 8u) && ((unsigned)hh < 96u);
        goff[p4] = ok ? (dd*9216 + hh*96 + q*4) : -1;
        lwr[p4]  = row*104 + 2 + q*4;   // w=0 at idx 2 (even -> b64 writes)
    }

    // ---- B-compute decode for this thread's Bb entry ----
    int bpart = tid >> 7;            // 0 = Whi, 1 = Wlo
    int bfr   = (tid >> 6) & 1;      // frag index
    int blane = tid & 63;
    int bn    = blane & 15, bkg = blane >> 4;
    int bs    = bn >> 2,    bo  = bn & 3;

    f32x4 acc[6] = {};               // 6 w-tiles per wave (static indexing)

    #pragma unroll 1
    for (int it = 0; it < 36; ++it) {
        int ci = it / 9, ij = it % 9;
        int i  = ij / 3, j  = ij % 3;
        const float* xp = xg + (size_t)b*18874368 + (size_t)ci*4718592
                             + (size_t)(c + i)*589824
                             + (size_t)(t + j)*73728;

        __syncthreads();   // previous iter's readers done before overwrite

        // ---- stage x: load f32, split to (hi16|lo16), write LDS ----
        #pragma unroll
        for (int p4 = 0; p4 < 4; ++p4) {
            if (goff[p4] >= 0) {
                float4 v = *(const float4*)(xp + goff[p4]);
                uint32_t a0 = packsplit(v.x), a1 = packsplit(v.y);
                uint32_t a2 = packsplit(v.z), a3 = packsplit(v.w);
                *(uint2*)&xs[lwr[p4]]     = make_uint2(a0, a1);
                *(uint2*)&xs[lwr[p4] + 2] = make_uint2(a2, a3);
            }
        }

        // ---- stage B: one uint4 (8 bf16) per thread ----
        {
            const float* wq = Wg + ij*432 + bo*108 + ci*27;
            uint32_t wd0 = 0u, wd1 = 0u, wd2 = 0u, wd3 = 0u;
            #pragma unroll
            for (int e = 0; e < 8; ++e) {
                int k = bfr*32 + bkg*8 + e;
                float val = 0.f;
                if (k < 54) {
                    int p  = k / 9, r9 = k % 9;
                    int kh = r9 / 3, kw = r9 % 3;
                    int kd = p - bs;             // d-masking folded into B
                    if (kd >= 0 && kd <= 2) val = wq[kd*9 + kh*3 + kw];
                }
                uint32_t bv = __float_as_uint(val);
                uint32_t hi = bv & 0xFFFF0000u;
                uint32_t h16;
                if (bpart == 0) {
                    h16 = hi >> 16;
                } else {
                    float lo = val - __uint_as_float(hi);
                    h16 = __float_as_uint(lo) >> 16;
                }
                uint32_t sh = h16 << ((e & 1) * 16);
                if ((e >> 1) == 0) wd0 |= sh;
                else if ((e >> 1) == 1) wd1 |= sh;
                else if ((e >> 1) == 2) wd2 |= sh;
                else wd3 |= sh;
            }
            Bb[tid] = make_uint4(wd0, wd1, wd2, wd3);
        }

        __syncthreads();

        // ---- load B-frags (broadcast-free linear b128 reads) ----
        const bf16x8* bp = (const bf16x8*)Bb;
        bf16x8 Bh0 = bp[lane];
        bf16x8 Bh1 = bp[64 + lane];
        bf16x8 Bl0 = bp[128 + lane];
        bf16x8 Bl1 = bp[192 + lane];

        // ---- 6 w-tiles: build A-frags, 6 MFMAs each ----
        #pragma unroll
        for (int wt = 0; wt < 6; ++wt) {
            int wb = wt * 16;
            {   // f = 0 (k 0..31)
                uint32_t q0 = xs[wb + offs[0][0]], q1 = xs[wb + offs[0][1]];
                uint32_t q2 = xs[wb + offs[0][2]], q3 = xs[wb + offs[0][3]];
                uint32_t q4 = xs[wb + offs[0][4]], q5 = xs[wb + offs[0][5]];
                uint32_t q6 = xs[wb + offs[0][6]], q7 = xs[wb + offs[0][7]];
                FA ah, al;
                ah.u[0] = (q1 & 0xFFFF0000u) | (q0 >> 16);
                ah.u[1] = (q3 & 0xFFFF0000u) | (q2 >> 16);
                ah.u[2] = (q5 & 0xFFFF0000u) | (q4 >> 16);
                ah.u[3] = (q7 & 0xFFFF0000u) | (q6 >> 16);
                al.u[0] = (q1 << 16) | (q0 & 0xFFFFu);
                al.u[1] = (q3 << 16) | (q2 & 0xFFFFu);
                al.u[2] = (q5 << 16) | (q4 & 0xFFFFu);
                al.u[3] = (q7 << 16) | (q6 & 0xFFFFu);
                acc[wt] = __builtin_amdgcn_mfma_f32_16x16x32_bf16(ah.v, Bh0, acc[wt], 0, 0, 0);
                acc[wt] = __builtin_amdgcn_mfma_f32_16x16x32_bf16(al.v, Bh0, acc[wt], 0, 0, 0);
                acc[wt] = __builtin_amdgcn_mfma_f32_16x16x32_bf16(ah.v, Bl0, acc[wt], 0, 0, 0);
            }
            {   // f = 1 (k 32..63, incl. pad)
                uint32_t q0 = xs[wb + offs[1][0]], q1 = xs[wb + offs[1][1]];
                uint32_t q2 = xs[wb + offs[1][2]], q3 = xs[wb + offs[1][3]];
                uint32_t q4 = xs[wb + offs[1][4]], q5 = xs[wb + offs[1][5]];
                uint32_t q6 = xs[wb + offs[1][6]], q7 = xs[wb + offs[1][7]];
                FA ah, al;
                ah.u[0] = (q1 & 0xFFFF0000u) | (q0 >> 16);
                ah.u[1] = (q3 & 0xFFFF0000u) | (q2 >> 16);
                ah.u[2] = (q5 & 0xFFFF0000u) | (q4 >> 16);
                ah.u[3] = (q7 & 0xFFFF0000u) | (q6 >> 16);
                al.u[0] = (q1 << 16) | (q0 & 0xFFFFu);
                al.u[1] = (q3 << 16) | (q2 & 0xFFFFu);
                al.u[2] = (q5 << 16) | (q4 & 0xFFFFu);
                al.u[3] = (q7 << 16) | (q6 & 0xFFFFu);
                acc[wt] = __builtin_amdgcn_mfma_f32_16x16x32_bf16(ah.v, Bh1, acc[wt], 0, 0, 0);
                acc[wt] = __builtin_amdgcn_mfma_f32_16x16x32_bf16(al.v, Bh1, acc[wt], 0, 0, 0);
                acc[wt] = __builtin_amdgcn_mfma_f32_16x16x32_bf16(ah.v, Bl1, acc[wt], 0, 0, 0);
            }
        }
    }

    // ---- epilogue: D lane map: i = kg*4 + r (w offset), j = lane&15 = (s,o)
    int n  = lane & 15;
    int so = n >> 2, oo = n & 3;
    float mbo = 0.f;
    #pragma unroll
    for (int ij2 = 0; ij2 < 9; ++ij2) mbo += bg[ij2*4 + oo];
    mbo *= (1.0f / 9.0f);
    const float inv9 = 1.0f / 9.0f;

    size_t ob = (size_t)b*10616832 + (size_t)oo*2654208 + (size_t)c*442368
              + (size_t)t*73728 + (size_t)(dq*4 + so)*9216
              + (size_t)(h0 + wv)*96 + (size_t)(kg*4);
    #pragma unroll
    for (int wt = 0; wt < 6; ++wt) {
        float4 st;
        st.x = acc[wt][0] * inv9 + mbo;
        st.y = acc[wt][1] * inv9 + mbo;
        st.z = acc[wt][2] * inv9 + mbo;
        st.w = acc[wt][3] * inv9 + mbo;
        *(float4*)(outg + ob + wt*16) = st;
    }
}

extern "C" void kernel_launch(void* const* d_in, const int* in_sizes, int n_in,
                              void* d_out, int out_size, void* d_ws, size_t ws_size,
                              hipStream_t stream) {
    const float* x = (const float*)d_in[0];
    const float* W = (const float*)d_in[1];
    const float* b = (const float*)d_in[2];
    float* out = (float*)d_out;
    conv5d_mfma<<<3456, BLOCK, 0, stream>>>(x, W, b, out);
}

// Round 10
// 553.064 us; speedup vs baseline: 1.2531x; 1.2531x over previous
//
#include <hip/hip_runtime.h>

// x:   (2,4,8,8,8,96,96) fp32   strides: b 18874368, ci 4718592, cd 589824, t 73728, d 9216, h 96, w 1
// W:   (9,4,4,3,3,3)     fp32   strides: ij 432, o 108, ci 27, kd 9, kh 3, kw 1
// b:   (9,4)             fp32
// out: (2,4,6,6,8,96,96) fp32
//
// Round-10: r9 MFMA structure (validated correct) with the three measured
// overheads removed:
//  1. B-fragments precomputed by prep_kernel into ws (36 it x 4 frags x 64
//     lanes x uint4 = 147KB). r9 rebuilt them per-iter per-block: ~100 VALU
//     + 8 divergent VMEM per thread-iter, identical across all 3456 blocks.
//     Main loop now: 4 coalesced b128 loads (L2-resident table).
//  2. x-tile LDS layout transposed within-row: column u=w+1 stored at
//     P(u) = (u&3)*25 + (u>>2), stride 104. Staging writes become 4
//     lane-dense b32 (was 16B-stride -> 8-way conflicts); A-frag reads
//     spread over 16 distinct banks/group (~2-way = free). P is linear in
//     wt: P(u+16wt) = P(u)+4wt -> precomputed offsets + imm-offset reads.
//  3. A-frag pack via v_perm_b32 (1 op/word, CK byte-select idiom) instead
//     of 2-3 bitwise ops.
// Evidence: r9 counters: MfmaUtil 21.8% (=141us pipe, not the limit),
// BANK_CONFLICT 9.16e7 (~149us stall, write-side 8-way + read 2-way),
// VALUBusy 49.5% (~287us, B-build + repack). Targets all three.

#define BLOCK 256

typedef short bf16x8 __attribute__((ext_vector_type(8)));
typedef float f32x4  __attribute__((ext_vector_type(4)));

union FA { uint32_t u[4]; bf16x8 v; };
union FB { uint4 q; bf16x8 v; };

__device__ __forceinline__ uint32_t packsplit(float x) {
    uint32_t bx = __float_as_uint(x);
    uint32_t hi = bx & 0xFFFF0000u;
    float lo = x - __uint_as_float(hi);
    return hi | (__float_as_uint(lo) >> 16);
}

// B-fragment table: uint4[it(36)][frag(4)][lane(64)]
// frag: 0 = hi,f0   1 = hi,f1   2 = lo,f0   3 = lo,f1
__global__ void prep_kernel(const float* __restrict__ Wg, float* __restrict__ ws)
{
    int gidx = blockIdx.x * blockDim.x + threadIdx.x;   // 0..9215
    if (gidx >= 9216) return;
    int lane = gidx & 63;
    int frag = (gidx >> 6) & 3;
    int it   = gidx >> 8;
    int f    = frag & 1;
    int part = frag >> 1;            // 0 = hi, 1 = lo
    int ci = it / 9, ij = it % 9;
    int n  = lane & 15, kg = lane >> 4;
    int s  = n >> 2,   o  = n & 3;
    const float* wq = Wg + ij*432 + o*108 + ci*27;
    uint32_t wd[4] = {0u, 0u, 0u, 0u};
    for (int e = 0; e < 8; ++e) {
        int k = f*32 + kg*8 + e;
        float val = 0.f;
        if (k < 54) {
            int p  = k / 9, r9 = k % 9;
            int kh = r9 / 3, kw = r9 % 3;
            int kd = p - s;                       // d-mask folded into B
            if (kd >= 0 && kd <= 2) val = wq[kd*9 + kh*3 + kw];
        }
        uint32_t bv = __float_as_uint(val);
        uint32_t hi = bv & 0xFFFF0000u;
        uint32_t h16;
        if (part == 0) h16 = hi >> 16;
        else { float lo = val - __uint_as_float(hi); h16 = __float_as_uint(lo) >> 16; }
        wd[e >> 1] |= h16 << ((e & 1) * 16);
    }
    ((uint4*)ws)[gidx] = make_uint4(wd[0], wd[1], wd[2], wd[3]);
}

__global__ __launch_bounds__(256, 4) void conv5d_mfma(
    const float* __restrict__ xg,
    const float* __restrict__ wsB,
    const float* __restrict__ bg,
    float* __restrict__ outg)
{
    __shared__ uint32_t xs[36 * 104];   // packed split x, transposed rows: 14976 B

    // zero once: halo columns (P(0)=0, P(97)=49 per row) and out-of-range
    // planes/rows are never re-staged.
    for (int k = threadIdx.x; k < 36*104; k += BLOCK) xs[k] = 0u;

    // XCD-aware decode: 3456 = 72 (b,c,t) slabs x 2 dq x 24 h4
    int bi  = blockIdx.x;
    int xcd = bi & 7;
    int g   = bi >> 3;
    int slab = xcd*9 + g/48;
    int rr  = g % 48;
    int dq  = rr / 24;               // outputs d = dq*4 + s
    int h4  = rr % 24;
    int b   = slab / 36;
    int ct  = slab % 36;
    int c   = ct / 6;
    int t   = ct % 6;
    int h0  = h4 * 4;

    int tid  = threadIdx.x;
    int lane = tid & 63;
    int wv   = tid >> 6;             // wave -> h-row h0+wv
    int am   = lane & 15;            // A's m (w-position)
    int kg   = lane >> 4;            // k-group

    // ---- A-read offsets (loop-invariant): addr = offs[f][e] + 4*wt ----
    int offs[2][8];
    #pragma unroll
    for (int f = 0; f < 2; ++f) {
        #pragma unroll
        for (int e = 0; e < 8; ++e) {
            int k = f*32 + kg*8 + e;
            if (k < 54) {
                int p  = k / 9, r9 = k % 9;
                int kh = r9 / 3, kw = r9 % 3;
                int row = p*6 + wv + kh;
                int ub  = am + kw;               // u = ub + 16*wt
                offs[f][e] = row*104 + (ub & 3)*25 + (ub >> 2);
            } else {
                offs[f][e] = 0;                  // pad: B=0 there
            }
        }
    }

    // ---- staging descriptors: 36 rows x 24 float4, 4 passes ----
    int goff[4], lbs[4];
    #pragma unroll
    for (int p4 = 0; p4 < 4; ++p4) {
        int u   = tid + p4*BLOCK;
        int row = u / 24, q = u % 24;
        int pp  = row / 6, hq = row % 6;
        int dd  = dq*4 - 1 + pp;
        int hh  = h0 - 1 + hq;
        bool ok = (u < 864) && ((unsigned)dd < 8u) && ((unsigned)hh < 96u);
        goff[p4] = ok ? (dd*9216 + hh*96 + q*4) : -1;
        lbs[p4]  = row*104 + q;      // writes at +1, +25, +50, +75
    }

    f32x4 acc[6] = {};

    #pragma unroll 1
    for (int it = 0; it < 36; ++it) {
        int ci = it / 9, ij = it % 9;
        int i  = ij / 3, j  = ij % 3;
        const float* xp = xg + (size_t)b*18874368 + (size_t)ci*4718592
                             + (size_t)(c + i)*589824
                             + (size_t)(t + j)*73728;

        // issue this iter's global loads early: in flight across barrier 1
        float4 v0, v1, v2, v3;
        if (goff[0] >= 0) v0 = *(const float4*)(xp + goff[0]);
        if (goff[1] >= 0) v1 = *(const float4*)(xp + goff[1]);
        if (goff[2] >= 0) v2 = *(const float4*)(xp + goff[2]);
        if (goff[3] >= 0) v3 = *(const float4*)(xp + goff[3]);

        // B-fragments from precomputed table (L2-hot, coalesced b128)
        const uint4* tb = (const uint4*)wsB + it*256 + lane;
        FB Bh0, Bh1, Bl0, Bl1;
        Bh0.q = tb[0];
        Bh1.q = tb[64];
        Bl0.q = tb[128];
        Bl1.q = tb[192];

        __syncthreads();   // previous iter's readers done before overwrite

        // ---- stage: transposed-row writes (lane-dense, conflict-free) ----
        if (goff[0] >= 0) {
            xs[lbs[0] + 25] = packsplit(v0.x);  xs[lbs[0] + 50] = packsplit(v0.y);
            xs[lbs[0] + 75] = packsplit(v0.z);  xs[lbs[0] +  1] = packsplit(v0.w);
        }
        if (goff[1] >= 0) {
            xs[lbs[1] + 25] = packsplit(v1.x);  xs[lbs[1] + 50] = packsplit(v1.y);
            xs[lbs[1] + 75] = packsplit(v1.z);  xs[lbs[1] +  1] = packsplit(v1.w);
        }
        if (goff[2] >= 0) {
            xs[lbs[2] + 25] = packsplit(v2.x);  xs[lbs[2] + 50] = packsplit(v2.y);
            xs[lbs[2] + 75] = packsplit(v2.z);  xs[lbs[2] +  1] = packsplit(v2.w);
        }
        if (goff[3] >= 0) {
            xs[lbs[3] + 25] = packsplit(v3.x);  xs[lbs[3] + 50] = packsplit(v3.y);
            xs[lbs[3] + 75] = packsplit(v3.z);  xs[lbs[3] +  1] = packsplit(v3.w);
        }

        __syncthreads();

        // ---- compute: 6 w-tiles x (read 16 b32, pack 8 v_perm, 6 MFMA) ----
        #pragma unroll
        for (int wt = 0; wt < 6; ++wt) {
            int wb = wt * 4;
            {   // f = 0 (k 0..31)
                uint32_t q0 = xs[wb + offs[0][0]], q1 = xs[wb + offs[0][1]];
                uint32_t q2 = xs[wb + offs[0][2]], q3 = xs[wb + offs[0][3]];
                uint32_t q4 = xs[wb + offs[0][4]], q5 = xs[wb + offs[0][5]];
                uint32_t q6 = xs[wb + offs[0][6]], q7 = xs[wb + offs[0][7]];
                FA ah, al;
                ah.u[0] = __builtin_amdgcn_perm(q1, q0, 0x07060302u);
                ah.u[1] = __builtin_amdgcn_perm(q3, q2, 0x07060302u);
                ah.u[2] = __builtin_amdgcn_perm(q5, q4, 0x07060302u);
                ah.u[3] = __builtin_amdgcn_perm(q7, q6, 0x07060302u);
                al.u[0] = __builtin_amdgcn_perm(q1, q0, 0x05040100u);
                al.u[1] = __builtin_amdgcn_perm(q3, q2, 0x05040100u);
                al.u[2] = __builtin_amdgcn_perm(q5, q4, 0x05040100u);
                al.u[3] = __builtin_amdgcn_perm(q7, q6, 0x05040100u);
                acc[wt] = __builtin_amdgcn_mfma_f32_16x16x32_bf16(ah.v, Bh0.v, acc[wt], 0, 0, 0);
                acc[wt] = __builtin_amdgcn_mfma_f32_16x16x32_bf16(al.v, Bh0.v, acc[wt], 0, 0, 0);
                acc[wt] = __builtin_amdgcn_mfma_f32_16x16x32_bf16(ah.v, Bl0.v, acc[wt], 0, 0, 0);
            }
            {   // f = 1 (k 32..63, incl. pad)
                uint32_t q0 = xs[wb + offs[1][0]], q1 = xs[wb + offs[1][1]];
                uint32_t q2 = xs[wb + offs[1][2]], q3 = xs[wb + offs[1][3]];
                uint32_t q4 = xs[wb + offs[1][4]], q5 = xs[wb + offs[1][5]];
                uint32_t q6 = xs[wb + offs[1][6]], q7 = xs[wb + offs[1][7]];
                FA ah, al;
                ah.u[0] = __builtin_amdgcn_perm(q1, q0, 0x07060302u);
                ah.u[1] = __builtin_amdgcn_perm(q3, q2, 0x07060302u);
                ah.u[2] = __builtin_amdgcn_perm(q5, q4, 0x07060302u);
                ah.u[3] = __builtin_amdgcn_perm(q7, q6, 0x07060302u);
                al.u[0] = __builtin_amdgcn_perm(q1, q0, 0x05040100u);
                al.u[1] = __builtin_amdgcn_perm(q3, q2, 0x05040100u);
                al.u[2] = __builtin_amdgcn_perm(q5, q4, 0x05040100u);
                al.u[3] = __builtin_amdgcn_perm(q7, q6, 0x05040100u);
                acc[wt] = __builtin_amdgcn_mfma_f32_16x16x32_bf16(ah.v, Bh1.v, acc[wt], 0, 0, 0);
                acc[wt] = __builtin_amdgcn_mfma_f32_16x16x32_bf16(al.v, Bh1.v, acc[wt], 0, 0, 0);
                acc[wt] = __builtin_amdgcn_mfma_f32_16x16x32_bf16(ah.v, Bl1.v, acc[wt], 0, 0, 0);
            }
        }
    }

    // ---- epilogue: D[i = kg*4 + r][j = lane&15 = (s,o)] ----
    int n  = lane & 15;
    int so = n >> 2, oo = n & 3;
    float mbo = 0.f;
    #pragma unroll
    for (int ij2 = 0; ij2 < 9; ++ij2) mbo += bg[ij2*4 + oo];
    mbo *= (1.0f / 9.0f);
    const float inv9 = 1.0f / 9.0f;

    size_t ob = (size_t)b*10616832 + (size_t)oo*2654208 + (size_t)c*442368
              + (size_t)t*73728 + (size_t)(dq*4 + so)*9216
              + (size_t)(h0 + wv)*96 + (size_t)(kg*4);
    #pragma unroll
    for (int wt = 0; wt < 6; ++wt) {
        float4 st;
        st.x = acc[wt][0] * inv9 + mbo;
        st.y = acc[wt][1] * inv9 + mbo;
        st.z = acc[wt][2] * inv9 + mbo;
        st.w = acc[wt][3] * inv9 + mbo;
        *(float4*)(outg + ob + wt*16) = st;
    }
}

extern "C" void kernel_launch(void* const* d_in, const int* in_sizes, int n_in,
                              void* d_out, int out_size, void* d_ws, size_t ws_size,
                              hipStream_t stream) {
    const float* x = (const float*)d_in[0];
    const float* W = (const float*)d_in[1];
    const float* b = (const float*)d_in[2];
    float* out = (float*)d_out;
    float* ws  = (float*)d_ws;

    prep_kernel<<<36, BLOCK, 0, stream>>>(W, ws);
    conv5d_mfma<<<3456, BLOCK, 0, stream>>>(x, ws, b, out);
}